// Round 5
// baseline (280.135 us; speedup 1.0000x reference)
//
#include <hip/hip_runtime.h>

// Native 4-wide float vector (works with __builtin_nontemporal_store,
// lowers to global_load/store_dwordx4).
typedef float f4 __attribute__((ext_vector_type(4)));

// Problem constants (from reference)
constexpr int OUTP = 32;        // OUT_PLANES
constexpr int INP  = 16;        // IN_PLANES
constexpr int REPS = 16;        // REP = 256/16
constexpr int BB   = 8;
constexpr int HW   = 32 * 32;   // 1024 pixels
constexpr int P4   = HW / 4;    // 256 f4 per channel
constexpr int OSTRIDE_F4 = INP * REPS * P4;  // 65536 f4 per o-plane (256 ch)
constexpr size_t OUT1_F4 = (size_t)BB * OUTP * OSTRIDE_F4;  // 16777216 f4

// Fused kernel, block = 1024 threads (16 waves):
//   blocks [0, 64):   out2. one thread per out2 f4 (65536 threads).
//   blocks [64, 576): out1. block -> (b, i, o-quarter). Thread (r0 = tid>>8,
//                     v = tid&255) holds x[b, i*16 + r0+4k, v] for k=0..3.
//                     LDS-reduce 16-r segment sum S[v]; then for each of the
//                     block's 8 o-planes, the block nontemporal-stores one
//                     CONTIGUOUS 64 KiB region (16r x 256v f4).
//                     R4 BUG FIX: o-stride is 65536 f4 (256 channels), not
//                     4096 (the 64 KiB region SIZE).
__global__ __launch_bounds__(1024, 8) void qconv_pw_fused(
    const f4* __restrict__ x,      // (B, 256, H, W) as f4: (b*256+c)*P4 + v
    const f4* __restrict__ x2,     // (B, 16, H, W)
    const float* __restrict__ w,   // (512,) == w2[o][i] at w[o*16+i]
    f4* __restrict__ out)          // out1 (B,8192,H,W) then relu_out2 (B,32,H,W)
{
    __shared__ f4 lds[4][P4];      // 16 KiB: partial r-sums per r0-slice

    const int blk = blockIdx.x;
    const int tid = threadIdx.x;

    if (blk >= 64) {
        // ---- out1 path ----
        const int wu = blk - 64;           // [0, 512)
        const int oq = wu & 3;             // o-quarter: o in [oq*8, oq*8+8)
        const int i  = (wu >> 2) & 15;
        const int b  = wu >> 6;
        const int r0 = tid >> 8;           // 0..3
        const int v  = tid & 255;          // f4 pixel index

        // Load 4 r-slices: r = r0 + 4k. Coalesced 1 KiB per wave-load.
        const f4* xbase = x + (size_t)(b * 256 + i * REPS) * P4 + v;
        f4 xv[4];
#pragma unroll
        for (int k = 0; k < 4; ++k) {
            xv[k] = xbase[(size_t)(r0 + 4 * k) * P4];
        }

        // Segment sum S[v] = sum over all 16 r of x[b, i*16+r, v].
        f4 part = xv[0] + xv[1] + xv[2] + xv[3];
        lds[r0][v] = part;
        __syncthreads();
        f4 S = lds[0][v] + lds[1][v] + lds[2][v] + lds[3][v];

        // Store 8 o-planes; each (b,o,i) region is 4096 f4 = 64 KiB
        // contiguous starting at (b*8192 + o*256 + i*16)*256.
        // Within region: offset = r*256 + v = j0 + k*1024 for r = r0+4k.
        const size_t cbase = (size_t)(b * (OUTP * INP * REPS) + i * REPS) * P4;
        const int j0 = r0 * P4 + v;        // == tid
#pragma unroll
        for (int oo = 0; oo < 8; ++oo) {
            const int o = oq * 8 + oo;
            const float wo = w[o * INP + i];   // wave-uniform -> scalar load
            f4 gw;
            gw.x = (wo * S.x > 0.f) ? wo : 0.f;
            gw.y = (wo * S.y > 0.f) ? wo : 0.f;
            gw.z = (wo * S.z > 0.f) ? wo : 0.f;
            gw.w = (wo * S.w > 0.f) ? wo : 0.f;
            const size_t obase = cbase + (size_t)o * OSTRIDE_F4 + j0;
#pragma unroll
            for (int k = 0; k < 4; ++k) {
                f4 res = xv[k] * gw;
                __builtin_nontemporal_store(res, &out[obase + (size_t)k * 1024]);
            }
        }
    } else {
        // ---- relu_out2 path ----
        const int t    = blk * 1024 + tid;         // [0, 65536)
        const int v    = t & (P4 - 1);             // f4 pixel index
        const int rest = t >> 8;                   // [0, 256) = B*OUTP
        const int o    = rest & (OUTP - 1);
        const int b    = rest >> 5;

        const f4* xb = x2 + (size_t)(b * INP) * P4 + v;
        f4 acc = (f4)(0.f);
#pragma unroll
        for (int i = 0; i < INP; ++i) {
            const float wo = w[o * INP + i];       // wave-uniform -> scalar load
            acc += xb[(size_t)i * P4] * wo;
        }
        acc.x = fmaxf(acc.x, 0.f);
        acc.y = fmaxf(acc.y, 0.f);
        acc.z = fmaxf(acc.z, 0.f);
        acc.w = fmaxf(acc.w, 0.f);

        out[OUT1_F4 + (size_t)(b * OUTP + o) * P4 + v] = acc;
    }
}

extern "C" void kernel_launch(void* const* d_in, const int* in_sizes, int n_in,
                              void* d_out, int out_size, void* d_ws, size_t ws_size,
                              hipStream_t stream) {
    const f4* x  = (const f4*)d_in[0];      // (8, 256, 32, 32) fp32
    const f4* x2 = (const f4*)d_in[1];      // (8, 16, 32, 32) fp32
    const float* w = (const float*)d_in[2]; // (512,1,1,1) fp32
    f4* out = (f4*)d_out;

    const int grid = 64 + 512;  // out2 blocks first, then out1 blocks
    qconv_pw_fused<<<grid, 1024, 0, stream>>>(x, x2, w, out);
}